// Round 7
// baseline (636.260 us; speedup 1.0000x reference)
//
#include <hip/hip_runtime.h>
#include <stdint.h>

#define DIM 768
#define HDIM 64
#define NHEADS 12
#define SEQ 2048
#define BATCH 4
#define NTOK (BATCH*SEQ)
#define FF 1536
// 0.125 (1/sqrt(64)) * log2(e): Q pre-scaled so softmax uses exp2 directly
#define QSCALE 0.1803368801111204f

typedef __bf16 bf16x8 __attribute__((ext_vector_type(8)));
typedef float f32x4 __attribute__((ext_vector_type(4)));
typedef unsigned short u16;
typedef unsigned int u32;

static __device__ __forceinline__ u16 f2bf(float f) {
  u32 u = __float_as_uint(f);
  u32 r = (u + 0x7fffu + ((u >> 16) & 1u)) >> 16;
  return (u16)r;
}

// ---------------- prep kernels ----------------

__global__ void conv_bf16(const float* __restrict__ in, u16* __restrict__ out, int n) {
  int i = (blockIdx.x * 256 + threadIdx.x) * 4;
  if (i < n) {
    float4 f = *(const float4*)(in + i);
    uint2 o;
    o.x = (u32)f2bf(f.x) | ((u32)f2bf(f.y) << 16);
    o.y = (u32)f2bf(f.z) | ((u32)f2bf(f.w) << 16);
    *(uint2*)(out + i) = o;
  }
}

// All weight transposes (fp32 [K][N] -> bf16 [N][K]) + bias concat in ONE kernel.
// Tiles: Wq/Wk/Wv 3x576, W1 1152, W2 1152 (=4032 blocks); blocks 4032..4040 do bias.
__global__ void prep_weights(const float* __restrict__ Wq, const float* __restrict__ Wk,
                             const float* __restrict__ Wv, const float* __restrict__ W1,
                             const float* __restrict__ W2, const float* __restrict__ bq,
                             const float* __restrict__ bk, const float* __restrict__ bv,
                             u16* __restrict__ Wqkvt, u16* __restrict__ W1t,
                             u16* __restrict__ W2t, float* __restrict__ bqkv) {
  const int bid = blockIdx.x;
  if (bid >= 4032) {
    int i = (bid - 4032) * 256 + threadIdx.x;
    if (i < DIM) bqkv[i] = bq[i];
    else if (i < 2 * DIM) bqkv[i] = bk[i - DIM];
    else if (i < 3 * DIM) bqkv[i] = bv[i - 2 * DIM];
    return;
  }
  const float* W; u16* dst; int K, N, tile;
  if (bid < 1728) {
    int z = bid / 576, t2 = bid - z * 576;
    W = z == 0 ? Wq : (z == 1 ? Wk : Wv);
    dst = Wqkvt + (size_t)z * DIM * DIM; K = DIM; N = DIM; tile = t2;
  } else if (bid < 2880) {
    W = W1; dst = W1t; K = DIM; N = FF; tile = bid - 1728;
  } else {
    W = W2; dst = W2t; K = FF; N = DIM; tile = bid - 2880;
  }
  const int ntx = N / 32;
  const int k0 = (tile / ntx) * 32, n0 = (tile - (tile / ntx) * ntx) * 32;
  __shared__ float t32[32][33];
  const int tx = threadIdx.x & 31, ty = threadIdx.x >> 5;
#pragma unroll
  for (int i = 0; i < 4; i++)
    t32[ty + 8 * i][tx] = W[(size_t)(k0 + ty + 8 * i) * N + n0 + tx];
  __syncthreads();
#pragma unroll
  for (int i = 0; i < 4; i++)
    dst[(size_t)(n0 + ty + 8 * i) * K + k0 + tx] = f2bf(t32[tx][ty + 8 * i]);
}

// ---------------- GEMM: C = A[MxK] * Bt[NxK]^T + bias ----------------
// Register-staged pipeline: global->VGPR issued one K-iter early, VGPR->LDS after barrier.
// MODE 3: relu bf16 [M][FF]  MODE 4: fp32 [M][DIM]
// MODE 5: fused QKV (N=2304): Q*QSCALE [bh][s][d]; K [bh][s][d]; V [bh][d][s]
// LDS rows of 64 u16 (8 chunks of 8), chunk XOR-swizzled by (row&7).

template<int MODE>
__launch_bounds__(256, 3)
__global__ void gemm128(const u16* __restrict__ A, const u16* __restrict__ Bt,
                        const float* __restrict__ bias, void* __restrict__ outp,
                        int K) {
  __shared__ u16 sA[128 * 64];
  __shared__ u16 sB[128 * 64];
  const int t = threadIdx.x;
  const int w = t >> 6;
  const int lane = t & 63;
  const int quad = lane >> 4;
  const int l15 = lane & 15;
  const int m0 = blockIdx.x * 128;
  const int n0 = blockIdx.y * 128;
  const int wr = (w & 1) * 64;
  const int wc = (w >> 1) * 64;

  f32x4 acc[4][4];
#pragma unroll
  for (int i = 0; i < 4; i++)
#pragma unroll
    for (int j = 0; j < 4; j++) acc[i][j] = (f32x4){0.f, 0.f, 0.f, 0.f};

  const int rowA = lane >> 3;
  const int colSw = ((lane & 7) ^ rowA) * 8;

  uint4 areg[4], breg[4];
#pragma unroll
  for (int j = 0; j < 4; j++) {
    int r0 = (j * 4 + w) * 8;
    areg[j] = *(const uint4*)(A + (size_t)(m0 + r0 + rowA) * K + colSw);
    breg[j] = *(const uint4*)(Bt + (size_t)(n0 + r0 + rowA) * K + colSw);
  }

  for (int k0 = 0; k0 < K; k0 += 64) {
    __syncthreads();            // drains vmcnt: regs for this iter are ready; LDS free
#pragma unroll
    for (int j = 0; j < 4; j++) {
      int r0 = (j * 4 + w) * 8;
      *(uint4*)(sA + r0 * 64 + lane * 8) = areg[j];
      *(uint4*)(sB + r0 * 64 + lane * 8) = breg[j];
    }
    __syncthreads();
    if (k0 + 64 < K) {          // prefetch next tile into registers (overlaps compute)
#pragma unroll
      for (int j = 0; j < 4; j++) {
        int r0 = (j * 4 + w) * 8;
        areg[j] = *(const uint4*)(A + (size_t)(m0 + r0 + rowA) * K + k0 + 64 + colSw);
        breg[j] = *(const uint4*)(Bt + (size_t)(n0 + r0 + rowA) * K + k0 + 64 + colSw);
      }
    }
#pragma unroll
    for (int ks = 0; ks < 64; ks += 32) {
      bf16x8 a[4], b[4];
#pragma unroll
      for (int i = 0; i < 4; i++)
        a[i] = *(const bf16x8*)(sA + (wr + i * 16 + l15) * 64 +
                                ((((ks >> 3) + quad) ^ (l15 & 7)) * 8));
#pragma unroll
      for (int j = 0; j < 4; j++)
        b[j] = *(const bf16x8*)(sB + (wc + j * 16 + l15) * 64 +
                                ((((ks >> 3) + quad) ^ (l15 & 7)) * 8));
#pragma unroll
      for (int i = 0; i < 4; i++)
#pragma unroll
        for (int j = 0; j < 4; j++)
          acc[i][j] = __builtin_amdgcn_mfma_f32_16x16x32_bf16(a[i], b[j], acc[i][j], 0, 0, 0);
    }
  }

#pragma unroll
  for (int i = 0; i < 4; i++) {
#pragma unroll
    for (int j = 0; j < 4; j++) {
#pragma unroll
      for (int r = 0; r < 4; r++) {
        int m = m0 + wr + i * 16 + quad * 4 + r;
        int n = n0 + wc + j * 16 + l15;
        float v = acc[i][j][r] + bias[n];
        if (MODE == 5) {
          int b = m >> 11, s = m & 2047;
          u16* o = (u16*)outp;
          if (n < DIM) {
            int h = n >> 6, d = n & 63;
            o[(((size_t)(b * NHEADS + h) * SEQ + s) << 6) + d] = f2bf(v * QSCALE);
          } else if (n < 2 * DIM) {
            int nn = n - DIM, h = nn >> 6, d = nn & 63;
            o[(size_t)NTOK * DIM + (((size_t)(b * NHEADS + h) * SEQ + s) << 6) + d] = f2bf(v);
          } else {
            int nn = n - 2 * DIM, h = nn >> 6, d = nn & 63;
            o[2 * (size_t)NTOK * DIM + ((size_t)(b * NHEADS + h) * HDIM + d) * SEQ + s] = f2bf(v);
          }
        } else if (MODE == 3) {
          ((u16*)outp)[(size_t)m * FF + n] = f2bf(fmaxf(v, 0.f));
        } else {
          ((float*)outp)[(size_t)m * DIM + n] = v;
        }
      }
    }
  }
}

// ---------------- flash attention v4 ----------------
// 128 q/block, S^T via swapped operands, b64 P-store, register-staged K/V pipeline.
// Grid 768 flat, XCD-swizzled. Q,K: [bh][s][d]; Vt: [bh][d][s]; Ctx: [tok][DIM] bf16.

__launch_bounds__(256, 3)
__global__ void attn(const u16* __restrict__ Q, const u16* __restrict__ Kb,
                     const u16* __restrict__ Vt, u16* __restrict__ Ctx) {
  __shared__ u16 sK[128 * 64];    // 16 KB, chunk swizzle ^ (row&7)
  __shared__ u16 sV[64 * 128];    // 16 KB, chunk swizzle ^ (row&15)
  __shared__ u16 sP[4][32 * 64];  // 16 KB, per-wave [q32][kv64], chunk swizzle ^ (l15&7)
  const int t = threadIdx.x, w = t >> 6, lane = t & 63;
  const int quad = lane >> 4, l15 = lane & 15;

  const int fid = blockIdx.x;           // 0..767
  const int xcd = fid & 7;
  const int idx = fid >> 3;
  const int bh = xcd + 8 * (idx >> 4);
  const int qb = idx & 15;
  const size_t qkbase = (size_t)bh * SEQ * HDIM;
  const int q0 = qb * 128 + w * 32;

  bf16x8 qf[2][2];
#pragma unroll
  for (int i = 0; i < 2; i++)
#pragma unroll
    for (int ks = 0; ks < 2; ks++)
      qf[i][ks] = *(const bf16x8*)(Q + qkbase + (size_t)(q0 + i * 16 + l15) * HDIM +
                                   ks * 32 + quad * 8);

  f32x4 o[2][4];
#pragma unroll
  for (int i = 0; i < 2; i++)
#pragma unroll
    for (int di = 0; di < 4; di++) o[i][di] = (f32x4){0.f, 0.f, 0.f, 0.f};
  float rs[2] = {0.f, 0.f};

  const int rowK = lane >> 3;
  const int colKsw = ((lane & 7) ^ rowK) * 8;
  const int rowVl = lane >> 4;
  const int chV = lane & 15;
  const int swz = l15 & 7;

  uint4 kreg[4], vreg[4];
#pragma unroll
  for (int j = 0; j < 4; j++) {
    int rk = (j * 4 + w) * 8;
    kreg[j] = *(const uint4*)(Kb + qkbase + (size_t)(rk + rowK) * HDIM + colKsw);
    int rV = (j * 4 + w) * 4 + rowVl;
    vreg[j] = *(const uint4*)(Vt + qkbase + (size_t)rV * SEQ + ((chV ^ (rV & 15)) * 8));
  }

  for (int kt = 0; kt < SEQ / 128; kt++) {
    __syncthreads();            // regs for kt landed (drain); LDS free after prior reads
#pragma unroll
    for (int j = 0; j < 4; j++) {
      int rk = (j * 4 + w) * 8;
      *(uint4*)(sK + rk * 64 + lane * 8) = kreg[j];
      int rv = (j * 4 + w) * 4;
      *(uint4*)(sV + rv * 128 + lane * 8) = vreg[j];
    }
    __syncthreads();
    if (kt < SEQ / 128 - 1) {   // prefetch kt+1 into registers — overlaps compute
#pragma unroll
      for (int j = 0; j < 4; j++) {
        int rk = (j * 4 + w) * 8;
        kreg[j] = *(const uint4*)(Kb + qkbase +
                                  (size_t)((kt + 1) * 128 + rk + rowK) * HDIM + colKsw);
        int rV = (j * 4 + w) * 4 + rowVl;
        vreg[j] = *(const uint4*)(Vt + qkbase + (size_t)rV * SEQ + (kt + 1) * 128 +
                                  ((chV ^ (rV & 15)) * 8));
      }
    }

    u16* pw = sP[w];
#pragma unroll
    for (int hh = 0; hh < 2; hh++) {
      f32x4 sc[2][4];
#pragma unroll
      for (int n4 = 0; n4 < 4; n4++) {
        int kr = (hh * 4 + n4) * 16;
        bf16x8 a0 = *(const bf16x8*)(sK + (kr + l15) * 64 + ((quad ^ swz) * 8));
        bf16x8 a1 = *(const bf16x8*)(sK + (kr + l15) * 64 + (((4 + quad) ^ swz) * 8));
#pragma unroll
        for (int i = 0; i < 2; i++) {
          f32x4 c = (f32x4){0.f, 0.f, 0.f, 0.f};
          c = __builtin_amdgcn_mfma_f32_16x16x32_bf16(a0, qf[i][0], c, 0, 0, 0);
          c = __builtin_amdgcn_mfma_f32_16x16x32_bf16(a1, qf[i][1], c, 0, 0, 0);
          sc[i][n4] = c;
        }
      }
#pragma unroll
      for (int i = 0; i < 2; i++) {
        int row = i * 16 + l15;
#pragma unroll
        for (int n4 = 0; n4 < 4; n4++) {
          float p0 = __builtin_amdgcn_exp2f(sc[i][n4][0]);
          float p1 = __builtin_amdgcn_exp2f(sc[i][n4][1]);
          float p2 = __builtin_amdgcn_exp2f(sc[i][n4][2]);
          float p3 = __builtin_amdgcn_exp2f(sc[i][n4][3]);
          rs[i] += (p0 + p1) + (p2 + p3);
          // bf16 pack (round-half-up) via v_perm: D = {hi16(b),hi16(a)}
          u32 lo = __builtin_amdgcn_perm(__float_as_uint(p1) + 0x8000u,
                                         __float_as_uint(p0) + 0x8000u, 0x07060302u);
          u32 hi = __builtin_amdgcn_perm(__float_as_uint(p3) + 0x8000u,
                                         __float_as_uint(p2) + 0x8000u, 0x07060302u);
          int cp = (n4 * 2 + (quad >> 1)) ^ swz;
          *(uint2*)(pw + row * 64 + cp * 8 + (quad & 1) * 4) = (uint2){lo, hi};
        }
      }
#pragma unroll
      for (int ks = 0; ks < 2; ks++) {
        bf16x8 ap[2];
#pragma unroll
        for (int i = 0; i < 2; i++) {
          int row = i * 16 + l15;
          int cp = (ks * 4 + quad) ^ swz;
          ap[i] = *(const bf16x8*)(pw + row * 64 + cp * 8);
        }
#pragma unroll
        for (int di = 0; di < 4; di++) {
          bf16x8 b = *(const bf16x8*)(sV + (di * 16 + l15) * 128 +
                                      (((hh * 8 + ks * 4 + quad) ^ l15) * 8));
          o[0][di] = __builtin_amdgcn_mfma_f32_16x16x32_bf16(ap[0], b, o[0][di], 0, 0, 0);
          o[1][di] = __builtin_amdgcn_mfma_f32_16x16x32_bf16(ap[1], b, o[1][di], 0, 0, 0);
        }
      }
    }
  }

  float rsum[2];
#pragma unroll
  for (int i = 0; i < 2; i++) {
    float s = rs[i];
    s += __shfl_xor(s, 16);
    s += __shfl_xor(s, 32);
    rsum[i] = s;
  }
  int b = bh / NHEADS, h = bh - b * NHEADS;
#pragma unroll
  for (int i = 0; i < 2; i++) {
#pragma unroll
    for (int r = 0; r < 4; r++) {
      float inv = 1.f / __shfl(rsum[i], quad * 4 + r);
      int q = q0 + i * 16 + quad * 4 + r;
      size_t base = (size_t)(b * SEQ + q) * DIM + h * HDIM;
#pragma unroll
      for (int di = 0; di < 4; di++)
        Ctx[base + di * 16 + l15] = f2bf(o[i][di][r] * inv);
    }
  }
}

// ---------------- residual + LayerNorm: one wave per token ----------------

__launch_bounds__(64)
__global__ void ln_kernel(const float* __restrict__ x, const float* __restrict__ y,
                          const float* __restrict__ gamma, const float* __restrict__ beta,
                          float* __restrict__ out) {
  const int tok = blockIdx.x;
  const int lane = threadIdx.x;
  const float4* X = (const float4*)(x + (size_t)tok * DIM);
  const float4* Y = (const float4*)(y + (size_t)tok * DIM);
  const float4* G = (const float4*)gamma;
  const float4* Bt = (const float4*)beta;
  float4* O = (float4*)(out + (size_t)tok * DIM);

  float4 h[3];
  float s = 0.f;
#pragma unroll
  for (int i = 0; i < 3; i++) {
    float4 a = X[i * 64 + lane], b = Y[i * 64 + lane];
    h[i].x = a.x + b.x; h[i].y = a.y + b.y; h[i].z = a.z + b.z; h[i].w = a.w + b.w;
    s += h[i].x + h[i].y + h[i].z + h[i].w;
  }
#pragma unroll
  for (int off = 32; off >= 1; off >>= 1) s += __shfl_xor(s, off);
  float mu = s * (1.f / DIM);
  float v = 0.f;
#pragma unroll
  for (int i = 0; i < 3; i++) {
    h[i].x -= mu; h[i].y -= mu; h[i].z -= mu; h[i].w -= mu;
    v += h[i].x * h[i].x + h[i].y * h[i].y + h[i].z * h[i].z + h[i].w * h[i].w;
  }
#pragma unroll
  for (int off = 32; off >= 1; off >>= 1) v += __shfl_xor(v, off);
  float rstd = rsqrtf(v * (1.f / DIM) + 1e-5f);
#pragma unroll
  for (int i = 0; i < 3; i++) {
    float4 g = G[i * 64 + lane], bt = Bt[i * 64 + lane];
    float4 r;
    r.x = h[i].x * rstd * g.x + bt.x;
    r.y = h[i].y * rstd * g.y + bt.y;
    r.z = h[i].z * rstd * g.z + bt.z;
    r.w = h[i].w * rstd * g.w + bt.w;
    O[i * 64 + lane] = r;
  }
}

// ---------------- launch ----------------

extern "C" void kernel_launch(void* const* d_in, const int* in_sizes, int n_in,
                              void* d_out, int out_size, void* d_ws, size_t ws_size,
                              hipStream_t stream) {
  const float* x  = (const float*)d_in[0];
  const float* Wq = (const float*)d_in[1];
  const float* bq = (const float*)d_in[2];
  const float* Wk = (const float*)d_in[3];
  const float* bk = (const float*)d_in[4];
  const float* Wv = (const float*)d_in[5];
  const float* bv = (const float*)d_in[6];
  const float* W1 = (const float*)d_in[7];
  const float* b1 = (const float*)d_in[8];
  const float* W2 = (const float*)d_in[9];
  const float* b2 = (const float*)d_in[10];
  const float* gamma = (const float*)d_in[11];
  const float* beta  = (const float*)d_in[12];

  char* ws = (char*)d_ws;
  u16* xb   = (u16*)ws;           ws += (size_t)NTOK * DIM * 2;
  u16* Wqkvt = (u16*)ws;          ws += (size_t)DIM * DIM * 3 * 2;
  u16* W1t  = (u16*)ws;           ws += (size_t)DIM * FF * 2;
  u16* W2t  = (u16*)ws;           ws += (size_t)DIM * FF * 2;
  float* bqkv = (float*)ws;       ws += (size_t)3 * DIM * 4;
  u16* Qb   = (u16*)ws;           ws += (size_t)NTOK * DIM * 2;   // Q,K,V contiguous
  u16* Kbf  = (u16*)ws;           ws += (size_t)NTOK * DIM * 2;
  u16* Vtb  = (u16*)ws;           ws += (size_t)NTOK * DIM * 2;
  u16* Ctx  = (u16*)ws;           ws += (size_t)NTOK * DIM * 2;
  u16* H1   = (u16*)ws;           ws += (size_t)NTOK * FF * 2;
  float* Y2 = (float*)ws;         ws += (size_t)NTOK * DIM * 4;

  // prep
  conv_bf16<<<(NTOK * DIM) / 1024, 256, 0, stream>>>(x, xb, NTOK * DIM);
  prep_weights<<<4041, 256, 0, stream>>>(Wq, Wk, Wv, W1, W2, bq, bk, bv,
                                         Wqkvt, W1t, W2t, bqkv);

  // fused QKV projection (N = 2304)
  gemm128<5><<<dim3(NTOK / 128, 3 * DIM / 128), 256, 0, stream>>>(xb, Wqkvt, bqkv, Qb, DIM);

  // attention (768 flat blocks, XCD-swizzled inside)
  attn<<<768, 256, 0, stream>>>(Qb, Kbf, Vtb, Ctx);

  // MLP
  gemm128<3><<<dim3(NTOK / 128, FF / 128), 256, 0, stream>>>(Ctx, W1t, b1, H1, DIM);
  gemm128<4><<<dim3(NTOK / 128, DIM / 128), 256, 0, stream>>>(H1, W2t, b2, Y2, FF);

  // residual + LN
  ln_kernel<<<NTOK, 64, 0, stream>>>(x, Y2, gamma, beta, (float*)d_out);
}

// Round 8
// 345.738 us; speedup vs baseline: 1.8403x; 1.8403x over previous
//
#include <hip/hip_runtime.h>
#include <stdint.h>

#define DIM 768
#define HDIM 64
#define NHEADS 12
#define SEQ 2048
#define BATCH 4
#define NTOK (BATCH*SEQ)
#define FF 1536
// 0.125 (1/sqrt(64)) * log2(e): Q pre-scaled so softmax uses exp2 directly
#define QSCALE 0.1803368801111204f

typedef __bf16 bf16x8 __attribute__((ext_vector_type(8)));
typedef float f32x4 __attribute__((ext_vector_type(4)));
typedef unsigned short u16;
typedef unsigned int u32;

static __device__ __forceinline__ u16 f2bf(float f) {
  u32 u = __float_as_uint(f);
  u32 r = (u + 0x7fffu + ((u >> 16) & 1u)) >> 16;
  return (u16)r;
}

static __device__ __forceinline__ void async16(const void* g, void* l) {
  __builtin_amdgcn_global_load_lds(
      (const __attribute__((address_space(1))) u32*)g,
      (__attribute__((address_space(3))) u32*)l, 16, 0, 0);
}

// ---------------- prep kernels ----------------

__global__ void conv_bf16(const float* __restrict__ in, u16* __restrict__ out, int n) {
  int i = (blockIdx.x * 256 + threadIdx.x) * 4;
  if (i < n) {
    float4 f = *(const float4*)(in + i);
    uint2 o;
    o.x = (u32)f2bf(f.x) | ((u32)f2bf(f.y) << 16);
    o.y = (u32)f2bf(f.z) | ((u32)f2bf(f.w) << 16);
    *(uint2*)(out + i) = o;
  }
}

// All weight transposes (fp32 [K][N] -> bf16 [N][K]) + bias concat in ONE kernel.
// Tiles: Wq/Wk/Wv 3x576, W1 1152, W2 1152 (=4032 blocks); blocks 4032..4040 do bias.
__global__ void prep_weights(const float* __restrict__ Wq, const float* __restrict__ Wk,
                             const float* __restrict__ Wv, const float* __restrict__ W1,
                             const float* __restrict__ W2, const float* __restrict__ bq,
                             const float* __restrict__ bk, const float* __restrict__ bv,
                             u16* __restrict__ Wqkvt, u16* __restrict__ W1t,
                             u16* __restrict__ W2t, float* __restrict__ bqkv) {
  const int bid = blockIdx.x;
  if (bid >= 4032) {
    int i = (bid - 4032) * 256 + threadIdx.x;
    if (i < DIM) bqkv[i] = bq[i];
    else if (i < 2 * DIM) bqkv[i] = bk[i - DIM];
    else if (i < 3 * DIM) bqkv[i] = bv[i - 2 * DIM];
    return;
  }
  const float* W; u16* dst; int K, N, tile;
  if (bid < 1728) {
    int z = bid / 576, t2 = bid - z * 576;
    W = z == 0 ? Wq : (z == 1 ? Wk : Wv);
    dst = Wqkvt + (size_t)z * DIM * DIM; K = DIM; N = DIM; tile = t2;
  } else if (bid < 2880) {
    W = W1; dst = W1t; K = DIM; N = FF; tile = bid - 1728;
  } else {
    W = W2; dst = W2t; K = FF; N = DIM; tile = bid - 2880;
  }
  const int ntx = N / 32;
  const int k0 = (tile / ntx) * 32, n0 = (tile - (tile / ntx) * ntx) * 32;
  __shared__ float t32[32][33];
  const int tx = threadIdx.x & 31, ty = threadIdx.x >> 5;
#pragma unroll
  for (int i = 0; i < 4; i++)
    t32[ty + 8 * i][tx] = W[(size_t)(k0 + ty + 8 * i) * N + n0 + tx];
  __syncthreads();
#pragma unroll
  for (int i = 0; i < 4; i++)
    dst[(size_t)(n0 + ty + 8 * i) * K + k0 + tx] = f2bf(t32[tx][ty + 8 * i]);
}

// ---------------- GEMM: C = A[MxK] * Bt[NxK]^T + bias ----------------
// async16 (global_load_lds) staging — round-6 proven structure; register staging
// spilled acc to scratch (round-7 post-mortem: WRITE_SIZE 440 MB, 228 us).
// MODE 3: relu bf16 [M][FF]  MODE 4: fp32 [M][DIM]
// MODE 5: fused QKV (N=2304): Q*QSCALE [bh][s][d]; K [bh][s][d]; V [bh][d][s]
// LDS rows of 64 u16 (8 chunks of 8), chunk XOR-swizzled by (row&7).

template<int MODE>
__launch_bounds__(256, 3)
__global__ void gemm128(const u16* __restrict__ A, const u16* __restrict__ Bt,
                        const float* __restrict__ bias, void* __restrict__ outp,
                        int K) {
  __shared__ u16 sA[128 * 64];
  __shared__ u16 sB[128 * 64];
  const int t = threadIdx.x;
  const int w = t >> 6;
  const int lane = t & 63;
  const int quad = lane >> 4;
  const int l15 = lane & 15;
  const int m0 = blockIdx.x * 128;
  const int n0 = blockIdx.y * 128;
  const int wr = (w & 1) * 64;
  const int wc = (w >> 1) * 64;

  f32x4 acc[4][4];
#pragma unroll
  for (int i = 0; i < 4; i++)
#pragma unroll
    for (int j = 0; j < 4; j++) acc[i][j] = (f32x4){0.f, 0.f, 0.f, 0.f};

  const int rowA = lane >> 3;
  const int colSw = ((lane & 7) ^ rowA) * 8;

  for (int k0 = 0; k0 < K; k0 += 64) {
    __syncthreads();
#pragma unroll
    for (int j = 0; j < 4; j++) {
      int r0 = (j * 4 + w) * 8;
      async16(A + (size_t)(m0 + r0 + rowA) * K + k0 + colSw, sA + r0 * 64);
      async16(Bt + (size_t)(n0 + r0 + rowA) * K + k0 + colSw, sB + r0 * 64);
    }
    __builtin_amdgcn_s_waitcnt(0);
    __syncthreads();
#pragma unroll
    for (int ks = 0; ks < 64; ks += 32) {
      bf16x8 a[4], b[4];
#pragma unroll
      for (int i = 0; i < 4; i++)
        a[i] = *(const bf16x8*)(sA + (wr + i * 16 + l15) * 64 +
                                ((((ks >> 3) + quad) ^ (l15 & 7)) * 8));
#pragma unroll
      for (int j = 0; j < 4; j++)
        b[j] = *(const bf16x8*)(sB + (wc + j * 16 + l15) * 64 +
                                ((((ks >> 3) + quad) ^ (l15 & 7)) * 8));
#pragma unroll
      for (int i = 0; i < 4; i++)
#pragma unroll
        for (int j = 0; j < 4; j++)
          acc[i][j] = __builtin_amdgcn_mfma_f32_16x16x32_bf16(a[i], b[j], acc[i][j], 0, 0, 0);
    }
  }

#pragma unroll
  for (int i = 0; i < 4; i++) {
#pragma unroll
    for (int j = 0; j < 4; j++) {
#pragma unroll
      for (int r = 0; r < 4; r++) {
        int m = m0 + wr + i * 16 + quad * 4 + r;
        int n = n0 + wc + j * 16 + l15;
        float v = acc[i][j][r] + bias[n];
        if (MODE == 5) {
          int b = m >> 11, s = m & 2047;
          u16* o = (u16*)outp;
          if (n < DIM) {
            int h = n >> 6, d = n & 63;
            o[(((size_t)(b * NHEADS + h) * SEQ + s) << 6) + d] = f2bf(v * QSCALE);
          } else if (n < 2 * DIM) {
            int nn = n - DIM, h = nn >> 6, d = nn & 63;
            o[(size_t)NTOK * DIM + (((size_t)(b * NHEADS + h) * SEQ + s) << 6) + d] = f2bf(v);
          } else {
            int nn = n - 2 * DIM, h = nn >> 6, d = nn & 63;
            o[2 * (size_t)NTOK * DIM + ((size_t)(b * NHEADS + h) * HDIM + d) * SEQ + s] = f2bf(v);
          }
        } else if (MODE == 3) {
          ((u16*)outp)[(size_t)m * FF + n] = f2bf(fmaxf(v, 0.f));
        } else {
          ((float*)outp)[(size_t)m * DIM + n] = v;
        }
      }
    }
  }
}

// ---------------- flash attention v4 ----------------
// 128 q/block, S^T via swapped operands, b64 P-store, register-staged K/V pipeline
// (fits here: acc is only 32 VGPRs, unlike GEMM's 64).
// Grid 768 flat, XCD-swizzled. Q,K: [bh][s][d]; Vt: [bh][d][s]; Ctx: [tok][DIM] bf16.

__launch_bounds__(256, 3)
__global__ void attn(const u16* __restrict__ Q, const u16* __restrict__ Kb,
                     const u16* __restrict__ Vt, u16* __restrict__ Ctx) {
  __shared__ u16 sK[128 * 64];    // 16 KB, chunk swizzle ^ (row&7)
  __shared__ u16 sV[64 * 128];    // 16 KB, chunk swizzle ^ (row&15)
  __shared__ u16 sP[4][32 * 64];  // 16 KB, per-wave [q32][kv64], chunk swizzle ^ (l15&7)
  const int t = threadIdx.x, w = t >> 6, lane = t & 63;
  const int quad = lane >> 4, l15 = lane & 15;

  const int fid = blockIdx.x;           // 0..767
  const int xcd = fid & 7;
  const int idx = fid >> 3;
  const int bh = xcd + 8 * (idx >> 4);
  const int qb = idx & 15;
  const size_t qkbase = (size_t)bh * SEQ * HDIM;
  const int q0 = qb * 128 + w * 32;

  bf16x8 qf[2][2];
#pragma unroll
  for (int i = 0; i < 2; i++)
#pragma unroll
    for (int ks = 0; ks < 2; ks++)
      qf[i][ks] = *(const bf16x8*)(Q + qkbase + (size_t)(q0 + i * 16 + l15) * HDIM +
                                   ks * 32 + quad * 8);

  f32x4 o[2][4];
#pragma unroll
  for (int i = 0; i < 2; i++)
#pragma unroll
    for (int di = 0; di < 4; di++) o[i][di] = (f32x4){0.f, 0.f, 0.f, 0.f};
  float rs[2] = {0.f, 0.f};

  const int rowK = lane >> 3;
  const int colKsw = ((lane & 7) ^ rowK) * 8;
  const int rowVl = lane >> 4;
  const int chV = lane & 15;
  const int swz = l15 & 7;

  uint4 kreg[4], vreg[4];
#pragma unroll
  for (int j = 0; j < 4; j++) {
    int rk = (j * 4 + w) * 8;
    kreg[j] = *(const uint4*)(Kb + qkbase + (size_t)(rk + rowK) * HDIM + colKsw);
    int rV = (j * 4 + w) * 4 + rowVl;
    vreg[j] = *(const uint4*)(Vt + qkbase + (size_t)rV * SEQ + ((chV ^ (rV & 15)) * 8));
  }

  for (int kt = 0; kt < SEQ / 128; kt++) {
    __syncthreads();            // regs for kt landed (drain); LDS free after prior reads
#pragma unroll
    for (int j = 0; j < 4; j++) {
      int rk = (j * 4 + w) * 8;
      *(uint4*)(sK + rk * 64 + lane * 8) = kreg[j];
      int rv = (j * 4 + w) * 4;
      *(uint4*)(sV + rv * 128 + lane * 8) = vreg[j];
    }
    __syncthreads();
    if (kt < SEQ / 128 - 1) {   // prefetch kt+1 into registers — overlaps compute
#pragma unroll
      for (int j = 0; j < 4; j++) {
        int rk = (j * 4 + w) * 8;
        kreg[j] = *(const uint4*)(Kb + qkbase +
                                  (size_t)((kt + 1) * 128 + rk + rowK) * HDIM + colKsw);
        int rV = (j * 4 + w) * 4 + rowVl;
        vreg[j] = *(const uint4*)(Vt + qkbase + (size_t)rV * SEQ + (kt + 1) * 128 +
                                  ((chV ^ (rV & 15)) * 8));
      }
    }

    u16* pw = sP[w];
#pragma unroll
    for (int hh = 0; hh < 2; hh++) {
      f32x4 sc[2][4];
#pragma unroll
      for (int n4 = 0; n4 < 4; n4++) {
        int kr = (hh * 4 + n4) * 16;
        bf16x8 a0 = *(const bf16x8*)(sK + (kr + l15) * 64 + ((quad ^ swz) * 8));
        bf16x8 a1 = *(const bf16x8*)(sK + (kr + l15) * 64 + (((4 + quad) ^ swz) * 8));
#pragma unroll
        for (int i = 0; i < 2; i++) {
          f32x4 c = (f32x4){0.f, 0.f, 0.f, 0.f};
          c = __builtin_amdgcn_mfma_f32_16x16x32_bf16(a0, qf[i][0], c, 0, 0, 0);
          c = __builtin_amdgcn_mfma_f32_16x16x32_bf16(a1, qf[i][1], c, 0, 0, 0);
          sc[i][n4] = c;
        }
      }
#pragma unroll
      for (int i = 0; i < 2; i++) {
        int row = i * 16 + l15;
#pragma unroll
        for (int n4 = 0; n4 < 4; n4++) {
          float p0 = __builtin_amdgcn_exp2f(sc[i][n4][0]);
          float p1 = __builtin_amdgcn_exp2f(sc[i][n4][1]);
          float p2 = __builtin_amdgcn_exp2f(sc[i][n4][2]);
          float p3 = __builtin_amdgcn_exp2f(sc[i][n4][3]);
          rs[i] += (p0 + p1) + (p2 + p3);
          // bf16 pack (round-half-up) via v_perm: D = {hi16(b),hi16(a)}
          u32 lo = __builtin_amdgcn_perm(__float_as_uint(p1) + 0x8000u,
                                         __float_as_uint(p0) + 0x8000u, 0x07060302u);
          u32 hi = __builtin_amdgcn_perm(__float_as_uint(p3) + 0x8000u,
                                         __float_as_uint(p2) + 0x8000u, 0x07060302u);
          int cp = (n4 * 2 + (quad >> 1)) ^ swz;
          *(uint2*)(pw + row * 64 + cp * 8 + (quad & 1) * 4) = (uint2){lo, hi};
        }
      }
#pragma unroll
      for (int ks = 0; ks < 2; ks++) {
        bf16x8 ap[2];
#pragma unroll
        for (int i = 0; i < 2; i++) {
          int row = i * 16 + l15;
          int cp = (ks * 4 + quad) ^ swz;
          ap[i] = *(const bf16x8*)(pw + row * 64 + cp * 8);
        }
#pragma unroll
        for (int di = 0; di < 4; di++) {
          bf16x8 b = *(const bf16x8*)(sV + (di * 16 + l15) * 128 +
                                      (((hh * 8 + ks * 4 + quad) ^ l15) * 8));
          o[0][di] = __builtin_amdgcn_mfma_f32_16x16x32_bf16(ap[0], b, o[0][di], 0, 0, 0);
          o[1][di] = __builtin_amdgcn_mfma_f32_16x16x32_bf16(ap[1], b, o[1][di], 0, 0, 0);
        }
      }
    }
  }

  float rsum[2];
#pragma unroll
  for (int i = 0; i < 2; i++) {
    float s = rs[i];
    s += __shfl_xor(s, 16);
    s += __shfl_xor(s, 32);
    rsum[i] = s;
  }
  int b = bh / NHEADS, h = bh - b * NHEADS;
#pragma unroll
  for (int i = 0; i < 2; i++) {
#pragma unroll
    for (int r = 0; r < 4; r++) {
      float inv = 1.f / __shfl(rsum[i], quad * 4 + r);
      int q = q0 + i * 16 + quad * 4 + r;
      size_t base = (size_t)(b * SEQ + q) * DIM + h * HDIM;
#pragma unroll
      for (int di = 0; di < 4; di++)
        Ctx[base + di * 16 + l15] = f2bf(o[i][di][r] * inv);
    }
  }
}

// ---------------- residual + LayerNorm: one wave per token ----------------

__launch_bounds__(64)
__global__ void ln_kernel(const float* __restrict__ x, const float* __restrict__ y,
                          const float* __restrict__ gamma, const float* __restrict__ beta,
                          float* __restrict__ out) {
  const int tok = blockIdx.x;
  const int lane = threadIdx.x;
  const float4* X = (const float4*)(x + (size_t)tok * DIM);
  const float4* Y = (const float4*)(y + (size_t)tok * DIM);
  const float4* G = (const float4*)gamma;
  const float4* Bt = (const float4*)beta;
  float4* O = (float4*)(out + (size_t)tok * DIM);

  float4 h[3];
  float s = 0.f;
#pragma unroll
  for (int i = 0; i < 3; i++) {
    float4 a = X[i * 64 + lane], b = Y[i * 64 + lane];
    h[i].x = a.x + b.x; h[i].y = a.y + b.y; h[i].z = a.z + b.z; h[i].w = a.w + b.w;
    s += h[i].x + h[i].y + h[i].z + h[i].w;
  }
#pragma unroll
  for (int off = 32; off >= 1; off >>= 1) s += __shfl_xor(s, off);
  float mu = s * (1.f / DIM);
  float v = 0.f;
#pragma unroll
  for (int i = 0; i < 3; i++) {
    h[i].x -= mu; h[i].y -= mu; h[i].z -= mu; h[i].w -= mu;
    v += h[i].x * h[i].x + h[i].y * h[i].y + h[i].z * h[i].z + h[i].w * h[i].w;
  }
#pragma unroll
  for (int off = 32; off >= 1; off >>= 1) v += __shfl_xor(v, off);
  float rstd = rsqrtf(v * (1.f / DIM) + 1e-5f);
#pragma unroll
  for (int i = 0; i < 3; i++) {
    float4 g = G[i * 64 + lane], bt = Bt[i * 64 + lane];
    float4 r;
    r.x = h[i].x * rstd * g.x + bt.x;
    r.y = h[i].y * rstd * g.y + bt.y;
    r.z = h[i].z * rstd * g.z + bt.z;
    r.w = h[i].w * rstd * g.w + bt.w;
    O[i * 64 + lane] = r;
  }
}

// ---------------- launch ----------------

extern "C" void kernel_launch(void* const* d_in, const int* in_sizes, int n_in,
                              void* d_out, int out_size, void* d_ws, size_t ws_size,
                              hipStream_t stream) {
  const float* x  = (const float*)d_in[0];
  const float* Wq = (const float*)d_in[1];
  const float* bq = (const float*)d_in[2];
  const float* Wk = (const float*)d_in[3];
  const float* bk = (const float*)d_in[4];
  const float* Wv = (const float*)d_in[5];
  const float* bv = (const float*)d_in[6];
  const float* W1 = (const float*)d_in[7];
  const float* b1 = (const float*)d_in[8];
  const float* W2 = (const float*)d_in[9];
  const float* b2 = (const float*)d_in[10];
  const float* gamma = (const float*)d_in[11];
  const float* beta  = (const float*)d_in[12];

  char* ws = (char*)d_ws;
  u16* xb   = (u16*)ws;           ws += (size_t)NTOK * DIM * 2;
  u16* Wqkvt = (u16*)ws;          ws += (size_t)DIM * DIM * 3 * 2;
  u16* W1t  = (u16*)ws;           ws += (size_t)DIM * FF * 2;
  u16* W2t  = (u16*)ws;           ws += (size_t)DIM * FF * 2;
  float* bqkv = (float*)ws;       ws += (size_t)3 * DIM * 4;
  u16* Qb   = (u16*)ws;           ws += (size_t)NTOK * DIM * 2;   // Q,K,V contiguous
  u16* Kbf  = (u16*)ws;           ws += (size_t)NTOK * DIM * 2;
  u16* Vtb  = (u16*)ws;           ws += (size_t)NTOK * DIM * 2;
  u16* Ctx  = (u16*)ws;           ws += (size_t)NTOK * DIM * 2;
  u16* H1   = (u16*)ws;           ws += (size_t)NTOK * FF * 2;
  float* Y2 = (float*)ws;         ws += (size_t)NTOK * DIM * 4;

  // prep
  conv_bf16<<<(NTOK * DIM) / 1024, 256, 0, stream>>>(x, xb, NTOK * DIM);
  prep_weights<<<4041, 256, 0, stream>>>(Wq, Wk, Wv, W1, W2, bq, bk, bv,
                                         Wqkvt, W1t, W2t, bqkv);

  // fused QKV projection (N = 2304)
  gemm128<5><<<dim3(NTOK / 128, 3 * DIM / 128), 256, 0, stream>>>(xb, Wqkvt, bqkv, Qb, DIM);

  // attention (768 flat blocks, XCD-swizzled inside)
  attn<<<768, 256, 0, stream>>>(Qb, Kbf, Vtb, Ctx);

  // MLP
  gemm128<3><<<dim3(NTOK / 128, FF / 128), 256, 0, stream>>>(Ctx, W1t, b1, H1, DIM);
  gemm128<4><<<dim3(NTOK / 128, DIM / 128), 256, 0, stream>>>(H1, W2t, b2, Y2, FF);

  // residual + LN
  ln_kernel<<<NTOK, 64, 0, stream>>>(x, Y2, gamma, beta, (float*)d_out);
}

// Round 9
// 321.798 us; speedup vs baseline: 1.9772x; 1.0744x over previous
//
#include <hip/hip_runtime.h>
#include <stdint.h>

#define DIM 768
#define HDIM 64
#define NHEADS 12
#define SEQ 2048
#define BATCH 4
#define NTOK (BATCH*SEQ)
#define FF 1536
// 0.125 (1/sqrt(64)) * log2(e): Q pre-scaled so softmax uses exp2 directly
#define QSCALE 0.1803368801111204f

typedef __bf16 bf16x8 __attribute__((ext_vector_type(8)));
typedef float f32x4 __attribute__((ext_vector_type(4)));
typedef unsigned short u16;
typedef unsigned int u32;

static __device__ __forceinline__ u16 f2bf(float f) {
  u32 u = __float_as_uint(f);
  u32 r = (u + 0x7fffu + ((u >> 16) & 1u)) >> 16;
  return (u16)r;
}

// HARD CONSTRAINT (rounds 7+8): global->VGPR->LDS prefetch across __syncthreads
// gets spilled to scratch by this compiler (WRITE_SIZE 400+ MB, 2-3x regression).
// Only global_load_lds staging works.
static __device__ __forceinline__ void async16(const void* g, void* l) {
  __builtin_amdgcn_global_load_lds(
      (const __attribute__((address_space(1))) u32*)g,
      (__attribute__((address_space(3))) u32*)l, 16, 0, 0);
}

// ---------------- prep kernels ----------------

__global__ void conv_bf16(const float* __restrict__ in, u16* __restrict__ out, int n) {
  int i = (blockIdx.x * 256 + threadIdx.x) * 4;
  if (i < n) {
    float4 f = *(const float4*)(in + i);
    uint2 o;
    o.x = (u32)f2bf(f.x) | ((u32)f2bf(f.y) << 16);
    o.y = (u32)f2bf(f.z) | ((u32)f2bf(f.w) << 16);
    *(uint2*)(out + i) = o;
  }
}

// All weight transposes (fp32 [K][N] -> bf16 [N][K]) + bias concat in ONE kernel.
__global__ void prep_weights(const float* __restrict__ Wq, const float* __restrict__ Wk,
                             const float* __restrict__ Wv, const float* __restrict__ W1,
                             const float* __restrict__ W2, const float* __restrict__ bq,
                             const float* __restrict__ bk, const float* __restrict__ bv,
                             u16* __restrict__ Wqkvt, u16* __restrict__ W1t,
                             u16* __restrict__ W2t, float* __restrict__ bqkv) {
  const int bid = blockIdx.x;
  if (bid >= 4032) {
    int i = (bid - 4032) * 256 + threadIdx.x;
    if (i < DIM) bqkv[i] = bq[i];
    else if (i < 2 * DIM) bqkv[i] = bk[i - DIM];
    else if (i < 3 * DIM) bqkv[i] = bv[i - 2 * DIM];
    return;
  }
  const float* W; u16* dst; int K, N, tile;
  if (bid < 1728) {
    int z = bid / 576, t2 = bid - z * 576;
    W = z == 0 ? Wq : (z == 1 ? Wk : Wv);
    dst = Wqkvt + (size_t)z * DIM * DIM; K = DIM; N = DIM; tile = t2;
  } else if (bid < 2880) {
    W = W1; dst = W1t; K = DIM; N = FF; tile = bid - 1728;
  } else {
    W = W2; dst = W2t; K = FF; N = DIM; tile = bid - 2880;
  }
  const int ntx = N / 32;
  const int k0 = (tile / ntx) * 32, n0 = (tile - (tile / ntx) * ntx) * 32;
  __shared__ float t32[32][33];
  const int tx = threadIdx.x & 31, ty = threadIdx.x >> 5;
#pragma unroll
  for (int i = 0; i < 4; i++)
    t32[ty + 8 * i][tx] = W[(size_t)(k0 + ty + 8 * i) * N + n0 + tx];
  __syncthreads();
#pragma unroll
  for (int i = 0; i < 4; i++)
    dst[(size_t)(n0 + ty + 8 * i) * K + k0 + tx] = f2bf(t32[tx][ty + 8 * i]);
}

// ---------------- GEMM: C = A[MxK] * Bt[NxK]^T + bias ----------------
// async16 staging (round-6 proven). Grid is (N/128, M/128): consecutive blocks
// share the A-tile and the whole weight matrix fits one XCD's 4MB L2.
// MODE 3: relu bf16 [M][FF]  MODE 4: fp32 [M][DIM]
// MODE 5: fused QKV (N=2304): Q*QSCALE [bh][s][d]; K [bh][s][d]; V [bh][d][s]

template<int MODE>
__launch_bounds__(256, 3)
__global__ void gemm128(const u16* __restrict__ A, const u16* __restrict__ Bt,
                        const float* __restrict__ bias, void* __restrict__ outp,
                        int K) {
  __shared__ u16 sA[128 * 64];
  __shared__ u16 sB[128 * 64];
  const int t = threadIdx.x;
  const int w = t >> 6;
  const int lane = t & 63;
  const int quad = lane >> 4;
  const int l15 = lane & 15;
  const int m0 = blockIdx.y * 128;
  const int n0 = blockIdx.x * 128;
  const int wr = (w & 1) * 64;
  const int wc = (w >> 1) * 64;

  f32x4 acc[4][4];
#pragma unroll
  for (int i = 0; i < 4; i++)
#pragma unroll
    for (int j = 0; j < 4; j++) acc[i][j] = (f32x4){0.f, 0.f, 0.f, 0.f};

  const int rowA = lane >> 3;
  const int colSw = ((lane & 7) ^ rowA) * 8;

  for (int k0 = 0; k0 < K; k0 += 64) {
    __syncthreads();
#pragma unroll
    for (int j = 0; j < 4; j++) {
      int r0 = (j * 4 + w) * 8;
      async16(A + (size_t)(m0 + r0 + rowA) * K + k0 + colSw, sA + r0 * 64);
      async16(Bt + (size_t)(n0 + r0 + rowA) * K + k0 + colSw, sB + r0 * 64);
    }
    __builtin_amdgcn_s_waitcnt(0);
    __syncthreads();
#pragma unroll
    for (int ks = 0; ks < 64; ks += 32) {
      bf16x8 a[4], b[4];
#pragma unroll
      for (int i = 0; i < 4; i++)
        a[i] = *(const bf16x8*)(sA + (wr + i * 16 + l15) * 64 +
                                ((((ks >> 3) + quad) ^ (l15 & 7)) * 8));
#pragma unroll
      for (int j = 0; j < 4; j++)
        b[j] = *(const bf16x8*)(sB + (wc + j * 16 + l15) * 64 +
                                ((((ks >> 3) + quad) ^ (l15 & 7)) * 8));
#pragma unroll
      for (int i = 0; i < 4; i++)
#pragma unroll
        for (int j = 0; j < 4; j++)
          acc[i][j] = __builtin_amdgcn_mfma_f32_16x16x32_bf16(a[i], b[j], acc[i][j], 0, 0, 0);
    }
  }

#pragma unroll
  for (int i = 0; i < 4; i++) {
#pragma unroll
    for (int j = 0; j < 4; j++) {
#pragma unroll
      for (int r = 0; r < 4; r++) {
        int m = m0 + wr + i * 16 + quad * 4 + r;
        int n = n0 + wc + j * 16 + l15;
        float v = acc[i][j][r] + bias[n];
        if (MODE == 5) {
          int b = m >> 11, s = m & 2047;
          u16* o = (u16*)outp;
          if (n < DIM) {
            int h = n >> 6, d = n & 63;
            o[(((size_t)(b * NHEADS + h) * SEQ + s) << 6) + d] = f2bf(v * QSCALE);
          } else if (n < 2 * DIM) {
            int nn = n - DIM, h = nn >> 6, d = nn & 63;
            o[(size_t)NTOK * DIM + (((size_t)(b * NHEADS + h) * SEQ + s) << 6) + d] = f2bf(v);
          } else {
            int nn = n - 2 * DIM, h = nn >> 6, d = nn & 63;
            o[2 * (size_t)NTOK * DIM + ((size_t)(b * NHEADS + h) * HDIM + d) * SEQ + s] = f2bf(v);
          }
        } else if (MODE == 3) {
          ((u16*)outp)[(size_t)m * FF + n] = f2bf(fmaxf(v, 0.f));
        } else {
          ((float*)outp)[(size_t)m * DIM + n] = v;
        }
      }
    }
  }
}

// ---------------- flash attention (round-6 proven structure) ----------------
// 128 q/block, S^T via swapped operands, b64 P-store (v_perm pack), async16 staging.
// Grid 768 flat, XCD-swizzled. Q,K: [bh][s][d]; Vt: [bh][d][s]; Ctx: [tok][DIM] bf16.

__launch_bounds__(256, 3)
__global__ void attn(const u16* __restrict__ Q, const u16* __restrict__ Kb,
                     const u16* __restrict__ Vt, u16* __restrict__ Ctx) {
  __shared__ u16 sK[128 * 64];    // 16 KB, chunk swizzle ^ (row&7)
  __shared__ u16 sV[64 * 128];    // 16 KB, chunk swizzle ^ (row&15)
  __shared__ u16 sP[4][32 * 64];  // 16 KB, per-wave [q32][kv64], chunk swizzle ^ (l15&7)
  const int t = threadIdx.x, w = t >> 6, lane = t & 63;
  const int quad = lane >> 4, l15 = lane & 15;

  const int fid = blockIdx.x;           // 0..767
  const int xcd = fid & 7;
  const int idx = fid >> 3;
  const int bh = xcd + 8 * (idx >> 4);
  const int qb = idx & 15;
  const size_t qkbase = (size_t)bh * SEQ * HDIM;
  const int q0 = qb * 128 + w * 32;

  bf16x8 qf[2][2];
#pragma unroll
  for (int i = 0; i < 2; i++)
#pragma unroll
    for (int ks = 0; ks < 2; ks++)
      qf[i][ks] = *(const bf16x8*)(Q + qkbase + (size_t)(q0 + i * 16 + l15) * HDIM +
                                   ks * 32 + quad * 8);

  f32x4 o[2][4];
#pragma unroll
  for (int i = 0; i < 2; i++)
#pragma unroll
    for (int di = 0; di < 4; di++) o[i][di] = (f32x4){0.f, 0.f, 0.f, 0.f};
  float rs[2] = {0.f, 0.f};

  const int rowK = lane >> 3;
  const int colKsw = ((lane & 7) ^ rowK) * 8;
  const int rowVl = lane >> 4;
  const int chV = lane & 15;
  const int swz = l15 & 7;

  for (int kt = 0; kt < SEQ / 128; kt++) {
    __syncthreads();
#pragma unroll
    for (int j = 0; j < 4; j++) {
      int rk = (j * 4 + w) * 8;
      async16(Kb + qkbase + (size_t)(kt * 128 + rk + rowK) * HDIM + colKsw, sK + rk * 64);
      int rv = (j * 4 + w) * 4;
      int rV = rv + rowVl;
      int cV = (chV ^ (rV & 15)) * 8;
      async16(Vt + qkbase + (size_t)rV * SEQ + kt * 128 + cV, sV + rv * 128);
    }
    __builtin_amdgcn_s_waitcnt(0);
    __syncthreads();

    u16* pw = sP[w];
#pragma unroll
    for (int hh = 0; hh < 2; hh++) {
      f32x4 sc[2][4];
#pragma unroll
      for (int n4 = 0; n4 < 4; n4++) {
        int kr = (hh * 4 + n4) * 16;
        bf16x8 a0 = *(const bf16x8*)(sK + (kr + l15) * 64 + ((quad ^ swz) * 8));
        bf16x8 a1 = *(const bf16x8*)(sK + (kr + l15) * 64 + (((4 + quad) ^ swz) * 8));
#pragma unroll
        for (int i = 0; i < 2; i++) {
          f32x4 c = (f32x4){0.f, 0.f, 0.f, 0.f};
          c = __builtin_amdgcn_mfma_f32_16x16x32_bf16(a0, qf[i][0], c, 0, 0, 0);
          c = __builtin_amdgcn_mfma_f32_16x16x32_bf16(a1, qf[i][1], c, 0, 0, 0);
          sc[i][n4] = c;
        }
      }
#pragma unroll
      for (int i = 0; i < 2; i++) {
        int row = i * 16 + l15;
#pragma unroll
        for (int n4 = 0; n4 < 4; n4++) {
          float p0 = __builtin_amdgcn_exp2f(sc[i][n4][0]);
          float p1 = __builtin_amdgcn_exp2f(sc[i][n4][1]);
          float p2 = __builtin_amdgcn_exp2f(sc[i][n4][2]);
          float p3 = __builtin_amdgcn_exp2f(sc[i][n4][3]);
          rs[i] += (p0 + p1) + (p2 + p3);
          // bf16 pack (round-half-up) via v_perm: D = {hi16(src0),hi16(src1)}
          u32 lo = __builtin_amdgcn_perm(__float_as_uint(p1) + 0x8000u,
                                         __float_as_uint(p0) + 0x8000u, 0x07060302u);
          u32 hi = __builtin_amdgcn_perm(__float_as_uint(p3) + 0x8000u,
                                         __float_as_uint(p2) + 0x8000u, 0x07060302u);
          int cp = (n4 * 2 + (quad >> 1)) ^ swz;
          *(uint2*)(pw + row * 64 + cp * 8 + (quad & 1) * 4) = (uint2){lo, hi};
        }
      }
#pragma unroll
      for (int ks = 0; ks < 2; ks++) {
        bf16x8 ap[2];
#pragma unroll
        for (int i = 0; i < 2; i++) {
          int row = i * 16 + l15;
          int cp = (ks * 4 + quad) ^ swz;
          ap[i] = *(const bf16x8*)(pw + row * 64 + cp * 8);
        }
#pragma unroll
        for (int di = 0; di < 4; di++) {
          bf16x8 b = *(const bf16x8*)(sV + (di * 16 + l15) * 128 +
                                      (((hh * 8 + ks * 4 + quad) ^ l15) * 8));
          o[0][di] = __builtin_amdgcn_mfma_f32_16x16x32_bf16(ap[0], b, o[0][di], 0, 0, 0);
          o[1][di] = __builtin_amdgcn_mfma_f32_16x16x32_bf16(ap[1], b, o[1][di], 0, 0, 0);
        }
      }
    }
  }

  float rsum[2];
#pragma unroll
  for (int i = 0; i < 2; i++) {
    float s = rs[i];
    s += __shfl_xor(s, 16);
    s += __shfl_xor(s, 32);
    rsum[i] = s;
  }
  int b = bh / NHEADS, h = bh - b * NHEADS;
#pragma unroll
  for (int i = 0; i < 2; i++) {
#pragma unroll
    for (int r = 0; r < 4; r++) {
      float inv = 1.f / __shfl(rsum[i], quad * 4 + r);
      int q = q0 + i * 16 + quad * 4 + r;
      size_t base = (size_t)(b * SEQ + q) * DIM + h * HDIM;
#pragma unroll
      for (int di = 0; di < 4; di++)
        Ctx[base + di * 16 + l15] = f2bf(o[i][di][r] * inv);
    }
  }
}

// ---------------- residual + LayerNorm: 4 tokens/block, one wave per token ----------------

__launch_bounds__(256)
__global__ void ln_kernel(const float* __restrict__ x, const float* __restrict__ y,
                          const float* __restrict__ gamma, const float* __restrict__ beta,
                          float* __restrict__ out) {
  const int tok = blockIdx.x * 4 + (threadIdx.x >> 6);
  const int lane = threadIdx.x & 63;
  const float4* X = (const float4*)(x + (size_t)tok * DIM);
  const float4* Y = (const float4*)(y + (size_t)tok * DIM);
  const float4* G = (const float4*)gamma;
  const float4* Bt = (const float4*)beta;
  float4* O = (float4*)(out + (size_t)tok * DIM);

  float4 h[3];
  float s = 0.f;
#pragma unroll
  for (int i = 0; i < 3; i++) {
    float4 a = X[i * 64 + lane], b = Y[i * 64 + lane];
    h[i].x = a.x + b.x; h[i].y = a.y + b.y; h[i].z = a.z + b.z; h[i].w = a.w + b.w;
    s += h[i].x + h[i].y + h[i].z + h[i].w;
  }
#pragma unroll
  for (int off = 32; off >= 1; off >>= 1) s += __shfl_xor(s, off);
  float mu = s * (1.f / DIM);
  float v = 0.f;
#pragma unroll
  for (int i = 0; i < 3; i++) {
    h[i].x -= mu; h[i].y -= mu; h[i].z -= mu; h[i].w -= mu;
    v += h[i].x * h[i].x + h[i].y * h[i].y + h[i].z * h[i].z + h[i].w * h[i].w;
  }
#pragma unroll
  for (int off = 32; off >= 1; off >>= 1) v += __shfl_xor(v, off);
  float rstd = rsqrtf(v * (1.f / DIM) + 1e-5f);
#pragma unroll
  for (int i = 0; i < 3; i++) {
    float4 g = G[i * 64 + lane], bt = Bt[i * 64 + lane];
    float4 r;
    r.x = h[i].x * rstd * g.x + bt.x;
    r.y = h[i].y * rstd * g.y + bt.y;
    r.z = h[i].z * rstd * g.z + bt.z;
    r.w = h[i].w * rstd * g.w + bt.w;
    O[i * 64 + lane] = r;
  }
}

// ---------------- launch ----------------

extern "C" void kernel_launch(void* const* d_in, const int* in_sizes, int n_in,
                              void* d_out, int out_size, void* d_ws, size_t ws_size,
                              hipStream_t stream) {
  const float* x  = (const float*)d_in[0];
  const float* Wq = (const float*)d_in[1];
  const float* bq = (const float*)d_in[2];
  const float* Wk = (const float*)d_in[3];
  const float* bk = (const float*)d_in[4];
  const float* Wv = (const float*)d_in[5];
  const float* bv = (const float*)d_in[6];
  const float* W1 = (const float*)d_in[7];
  const float* b1 = (const float*)d_in[8];
  const float* W2 = (const float*)d_in[9];
  const float* b2 = (const float*)d_in[10];
  const float* gamma = (const float*)d_in[11];
  const float* beta  = (const float*)d_in[12];

  char* ws = (char*)d_ws;
  u16* xb   = (u16*)ws;           ws += (size_t)NTOK * DIM * 2;
  u16* Wqkvt = (u16*)ws;          ws += (size_t)DIM * DIM * 3 * 2;
  u16* W1t  = (u16*)ws;           ws += (size_t)DIM * FF * 2;
  u16* W2t  = (u16*)ws;           ws += (size_t)DIM * FF * 2;
  float* bqkv = (float*)ws;       ws += (size_t)3 * DIM * 4;
  u16* Qb   = (u16*)ws;           ws += (size_t)NTOK * DIM * 2;   // Q,K,V contiguous
  u16* Kbf  = (u16*)ws;           ws += (size_t)NTOK * DIM * 2;
  u16* Vtb  = (u16*)ws;           ws += (size_t)NTOK * DIM * 2;
  u16* Ctx  = (u16*)ws;           ws += (size_t)NTOK * DIM * 2;
  u16* H1   = (u16*)ws;           ws += (size_t)NTOK * FF * 2;
  float* Y2 = (float*)ws;         ws += (size_t)NTOK * DIM * 4;

  // prep
  conv_bf16<<<(NTOK * DIM) / 1024, 256, 0, stream>>>(x, xb, NTOK * DIM);
  prep_weights<<<4041, 256, 0, stream>>>(Wq, Wk, Wv, W1, W2, bq, bk, bv,
                                         Wqkvt, W1t, W2t, bqkv);

  // fused QKV projection (N = 2304); grid = (N-tiles, M-tiles) for L2 locality
  gemm128<5><<<dim3(3 * DIM / 128, NTOK / 128), 256, 0, stream>>>(xb, Wqkvt, bqkv, Qb, DIM);

  // attention (768 flat blocks, XCD-swizzled inside)
  attn<<<768, 256, 0, stream>>>(Qb, Kbf, Vtb, Ctx);

  // MLP
  gemm128<3><<<dim3(FF / 128, NTOK / 128), 256, 0, stream>>>(Ctx, W1t, b1, H1, DIM);
  gemm128<4><<<dim3(DIM / 128, NTOK / 128), 256, 0, stream>>>(H1, W2t, b2, Y2, FF);

  // residual + LN
  ln_kernel<<<NTOK / 4, 256, 0, stream>>>(x, Y2, gamma, beta, (float*)d_out);
}

// Round 10
// 308.099 us; speedup vs baseline: 2.0651x; 1.0445x over previous
//
#include <hip/hip_runtime.h>
#include <stdint.h>

#define DIM 768
#define HDIM 64
#define NHEADS 12
#define SEQ 2048
#define BATCH 4
#define NTOK (BATCH*SEQ)
#define FF 1536
// 0.125 (1/sqrt(64)) * log2(e): Q pre-scaled so softmax uses exp2 directly
#define QSCALE 0.1803368801111204f

typedef __bf16 bf16x8 __attribute__((ext_vector_type(8)));
typedef float f32x4 __attribute__((ext_vector_type(4)));
typedef unsigned short u16;
typedef unsigned int u32;

static __device__ __forceinline__ u16 f2bf(float f) {
  u32 u = __float_as_uint(f);
  u32 r = (u + 0x7fffu + ((u >> 16) & 1u)) >> 16;
  return (u16)r;
}

// HARD CONSTRAINT (rounds 7+8): global->VGPR->LDS prefetch across __syncthreads
// gets spilled to scratch by this compiler (WRITE_SIZE 400+ MB, 2-3x regression).
// Only global_load_lds staging works.
static __device__ __forceinline__ void async16(const void* g, void* l) {
  __builtin_amdgcn_global_load_lds(
      (const __attribute__((address_space(1))) u32*)g,
      (__attribute__((address_space(3))) u32*)l, 16, 0, 0);
}

// ---------------- prep kernels ----------------

__global__ void conv_bf16(const float* __restrict__ in, u16* __restrict__ out, int n) {
  int i = (blockIdx.x * 256 + threadIdx.x) * 4;
  if (i < n) {
    float4 f = *(const float4*)(in + i);
    uint2 o;
    o.x = (u32)f2bf(f.x) | ((u32)f2bf(f.y) << 16);
    o.y = (u32)f2bf(f.z) | ((u32)f2bf(f.w) << 16);
    *(uint2*)(out + i) = o;
  }
}

// All weight transposes (fp32 [K][N] -> bf16 [N][K]) + bias concat in ONE kernel.
__global__ void prep_weights(const float* __restrict__ Wq, const float* __restrict__ Wk,
                             const float* __restrict__ Wv, const float* __restrict__ W1,
                             const float* __restrict__ W2, const float* __restrict__ bq,
                             const float* __restrict__ bk, const float* __restrict__ bv,
                             u16* __restrict__ Wqkvt, u16* __restrict__ W1t,
                             u16* __restrict__ W2t, float* __restrict__ bqkv) {
  const int bid = blockIdx.x;
  if (bid >= 4032) {
    int i = (bid - 4032) * 256 + threadIdx.x;
    if (i < DIM) bqkv[i] = bq[i];
    else if (i < 2 * DIM) bqkv[i] = bk[i - DIM];
    else if (i < 3 * DIM) bqkv[i] = bv[i - 2 * DIM];
    return;
  }
  const float* W; u16* dst; int K, N, tile;
  if (bid < 1728) {
    int z = bid / 576, t2 = bid - z * 576;
    W = z == 0 ? Wq : (z == 1 ? Wk : Wv);
    dst = Wqkvt + (size_t)z * DIM * DIM; K = DIM; N = DIM; tile = t2;
  } else if (bid < 2880) {
    W = W1; dst = W1t; K = DIM; N = FF; tile = bid - 1728;
  } else {
    W = W2; dst = W2t; K = FF; N = DIM; tile = bid - 2880;
  }
  const int ntx = N / 32;
  const int k0 = (tile / ntx) * 32, n0 = (tile - (tile / ntx) * ntx) * 32;
  __shared__ float t32[32][33];
  const int tx = threadIdx.x & 31, ty = threadIdx.x >> 5;
#pragma unroll
  for (int i = 0; i < 4; i++)
    t32[ty + 8 * i][tx] = W[(size_t)(k0 + ty + 8 * i) * N + n0 + tx];
  __syncthreads();
#pragma unroll
  for (int i = 0; i < 4; i++)
    dst[(size_t)(n0 + ty + 8 * i) * K + k0 + tx] = f2bf(t32[tx][ty + 8 * i]);
}

// ---------------- GEMM: C = A[MxK] * Bt[NxK]^T + bias ----------------
// async16 staging (proven). Flat grid with XCD swizzle (validated on attn, round 6:
// blockIdx%8 -> XCD round-robin): all NT N-tiles of an M-tile run consecutively on
// ONE XCD, so the A-tile is HBM-fetched once chip-wide and served from that XCD's L2.
// MODE 3: relu bf16 [M][FF]  MODE 4: fp32 [M][DIM]
// MODE 5: fused QKV (N=2304): Q*QSCALE [bh][s][d]; K [bh][s][d]; V [bh][d][s]

template<int MODE, int NT>
__launch_bounds__(256, 3)
__global__ void gemm128(const u16* __restrict__ A, const u16* __restrict__ Bt,
                        const float* __restrict__ bias, void* __restrict__ outp,
                        int K) {
  __shared__ u16 sA[128 * 64];
  __shared__ u16 sB[128 * 64];
  const int t = threadIdx.x;
  const int w = t >> 6;
  const int lane = t & 63;
  const int quad = lane >> 4;
  const int l15 = lane & 15;

  const int fid = blockIdx.x;
  const int xcd = fid & 7;
  const int j = fid >> 3;
  const int m0 = (xcd + 8 * (j / NT)) * 128;
  const int n0 = (j % NT) * 128;

  const int wr = (w & 1) * 64;
  const int wc = (w >> 1) * 64;

  f32x4 acc[4][4];
#pragma unroll
  for (int i = 0; i < 4; i++)
#pragma unroll
    for (int jj = 0; jj < 4; jj++) acc[i][jj] = (f32x4){0.f, 0.f, 0.f, 0.f};

  const int rowA = lane >> 3;
  const int colSw = ((lane & 7) ^ rowA) * 8;

  for (int k0 = 0; k0 < K; k0 += 64) {
    __syncthreads();
#pragma unroll
    for (int jj = 0; jj < 4; jj++) {
      int r0 = (jj * 4 + w) * 8;
      async16(A + (size_t)(m0 + r0 + rowA) * K + k0 + colSw, sA + r0 * 64);
      async16(Bt + (size_t)(n0 + r0 + rowA) * K + k0 + colSw, sB + r0 * 64);
    }
    __builtin_amdgcn_s_waitcnt(0);
    __syncthreads();
#pragma unroll
    for (int ks = 0; ks < 64; ks += 32) {
      bf16x8 a[4], b[4];
#pragma unroll
      for (int i = 0; i < 4; i++)
        a[i] = *(const bf16x8*)(sA + (wr + i * 16 + l15) * 64 +
                                ((((ks >> 3) + quad) ^ (l15 & 7)) * 8));
#pragma unroll
      for (int jj = 0; jj < 4; jj++)
        b[jj] = *(const bf16x8*)(sB + (wc + jj * 16 + l15) * 64 +
                                 ((((ks >> 3) + quad) ^ (l15 & 7)) * 8));
#pragma unroll
      for (int i = 0; i < 4; i++)
#pragma unroll
        for (int jj = 0; jj < 4; jj++)
          acc[i][jj] = __builtin_amdgcn_mfma_f32_16x16x32_bf16(a[i], b[jj], acc[i][jj], 0, 0, 0);
    }
  }

#pragma unroll
  for (int i = 0; i < 4; i++) {
#pragma unroll
    for (int jj = 0; jj < 4; jj++) {
#pragma unroll
      for (int r = 0; r < 4; r++) {
        int m = m0 + wr + i * 16 + quad * 4 + r;
        int n = n0 + wc + jj * 16 + l15;
        float v = acc[i][jj][r] + bias[n];
        if (MODE == 5) {
          int b = m >> 11, s = m & 2047;
          u16* o = (u16*)outp;
          if (n < DIM) {
            int h = n >> 6, d = n & 63;
            o[(((size_t)(b * NHEADS + h) * SEQ + s) << 6) + d] = f2bf(v * QSCALE);
          } else if (n < 2 * DIM) {
            int nn = n - DIM, h = nn >> 6, d = nn & 63;
            o[(size_t)NTOK * DIM + (((size_t)(b * NHEADS + h) * SEQ + s) << 6) + d] = f2bf(v);
          } else {
            int nn = n - 2 * DIM, h = nn >> 6, d = nn & 63;
            o[2 * (size_t)NTOK * DIM + ((size_t)(b * NHEADS + h) * HDIM + d) * SEQ + s] = f2bf(v);
          }
        } else if (MODE == 3) {
          ((u16*)outp)[(size_t)m * FF + n] = f2bf(fmaxf(v, 0.f));
        } else {
          ((float*)outp)[(size_t)m * DIM + n] = v;
        }
      }
    }
  }
}

// ---------------- flash attention (round-6 proven structure) ----------------
// 128 q/block, S^T via swapped operands, b64 P-store (v_perm pack), async16 staging.
// Grid 768 flat, XCD-swizzled. Q,K: [bh][s][d]; Vt: [bh][d][s]; Ctx: [tok][DIM] bf16.

__launch_bounds__(256, 3)
__global__ void attn(const u16* __restrict__ Q, const u16* __restrict__ Kb,
                     const u16* __restrict__ Vt, u16* __restrict__ Ctx) {
  __shared__ u16 sK[128 * 64];    // 16 KB, chunk swizzle ^ (row&7)
  __shared__ u16 sV[64 * 128];    // 16 KB, chunk swizzle ^ (row&15)
  __shared__ u16 sP[4][32 * 64];  // 16 KB, per-wave [q32][kv64], chunk swizzle ^ (l15&7)
  const int t = threadIdx.x, w = t >> 6, lane = t & 63;
  const int quad = lane >> 4, l15 = lane & 15;

  const int fid = blockIdx.x;           // 0..767
  const int xcd = fid & 7;
  const int idx = fid >> 3;
  const int bh = xcd + 8 * (idx >> 4);
  const int qb = idx & 15;
  const size_t qkbase = (size_t)bh * SEQ * HDIM;
  const int q0 = qb * 128 + w * 32;

  bf16x8 qf[2][2];
#pragma unroll
  for (int i = 0; i < 2; i++)
#pragma unroll
    for (int ks = 0; ks < 2; ks++)
      qf[i][ks] = *(const bf16x8*)(Q + qkbase + (size_t)(q0 + i * 16 + l15) * HDIM +
                                   ks * 32 + quad * 8);

  f32x4 o[2][4];
#pragma unroll
  for (int i = 0; i < 2; i++)
#pragma unroll
    for (int di = 0; di < 4; di++) o[i][di] = (f32x4){0.f, 0.f, 0.f, 0.f};
  float rs[2] = {0.f, 0.f};

  const int rowK = lane >> 3;
  const int colKsw = ((lane & 7) ^ rowK) * 8;
  const int rowVl = lane >> 4;
  const int chV = lane & 15;
  const int swz = l15 & 7;

  for (int kt = 0; kt < SEQ / 128; kt++) {
    __syncthreads();
#pragma unroll
    for (int j = 0; j < 4; j++) {
      int rk = (j * 4 + w) * 8;
      async16(Kb + qkbase + (size_t)(kt * 128 + rk + rowK) * HDIM + colKsw, sK + rk * 64);
      int rv = (j * 4 + w) * 4;
      int rV = rv + rowVl;
      int cV = (chV ^ (rV & 15)) * 8;
      async16(Vt + qkbase + (size_t)rV * SEQ + kt * 128 + cV, sV + rv * 128);
    }
    __builtin_amdgcn_s_waitcnt(0);
    __syncthreads();

    u16* pw = sP[w];
#pragma unroll
    for (int hh = 0; hh < 2; hh++) {
      f32x4 sc[2][4];
#pragma unroll
      for (int n4 = 0; n4 < 4; n4++) {
        int kr = (hh * 4 + n4) * 16;
        bf16x8 a0 = *(const bf16x8*)(sK + (kr + l15) * 64 + ((quad ^ swz) * 8));
        bf16x8 a1 = *(const bf16x8*)(sK + (kr + l15) * 64 + (((4 + quad) ^ swz) * 8));
#pragma unroll
        for (int i = 0; i < 2; i++) {
          f32x4 c = (f32x4){0.f, 0.f, 0.f, 0.f};
          c = __builtin_amdgcn_mfma_f32_16x16x32_bf16(a0, qf[i][0], c, 0, 0, 0);
          c = __builtin_amdgcn_mfma_f32_16x16x32_bf16(a1, qf[i][1], c, 0, 0, 0);
          sc[i][n4] = c;
        }
      }
#pragma unroll
      for (int i = 0; i < 2; i++) {
        int row = i * 16 + l15;
#pragma unroll
        for (int n4 = 0; n4 < 4; n4++) {
          float p0 = __builtin_amdgcn_exp2f(sc[i][n4][0]);
          float p1 = __builtin_amdgcn_exp2f(sc[i][n4][1]);
          float p2 = __builtin_amdgcn_exp2f(sc[i][n4][2]);
          float p3 = __builtin_amdgcn_exp2f(sc[i][n4][3]);
          rs[i] += (p0 + p1) + (p2 + p3);
          // bf16 pack (round-half-up) via v_perm: D = {hi16(src0),hi16(src1)}
          u32 lo = __builtin_amdgcn_perm(__float_as_uint(p1) + 0x8000u,
                                         __float_as_uint(p0) + 0x8000u, 0x07060302u);
          u32 hi = __builtin_amdgcn_perm(__float_as_uint(p3) + 0x8000u,
                                         __float_as_uint(p2) + 0x8000u, 0x07060302u);
          int cp = (n4 * 2 + (quad >> 1)) ^ swz;
          *(uint2*)(pw + row * 64 + cp * 8 + (quad & 1) * 4) = (uint2){lo, hi};
        }
      }
#pragma unroll
      for (int ks = 0; ks < 2; ks++) {
        bf16x8 ap[2];
#pragma unroll
        for (int i = 0; i < 2; i++) {
          int row = i * 16 + l15;
          int cp = (ks * 4 + quad) ^ swz;
          ap[i] = *(const bf16x8*)(pw + row * 64 + cp * 8);
        }
#pragma unroll
        for (int di = 0; di < 4; di++) {
          bf16x8 b = *(const bf16x8*)(sV + (di * 16 + l15) * 128 +
                                      (((hh * 8 + ks * 4 + quad) ^ l15) * 8));
          o[0][di] = __builtin_amdgcn_mfma_f32_16x16x32_bf16(ap[0], b, o[0][di], 0, 0, 0);
          o[1][di] = __builtin_amdgcn_mfma_f32_16x16x32_bf16(ap[1], b, o[1][di], 0, 0, 0);
        }
      }
    }
  }

  float rsum[2];
#pragma unroll
  for (int i = 0; i < 2; i++) {
    float s = rs[i];
    s += __shfl_xor(s, 16);
    s += __shfl_xor(s, 32);
    rsum[i] = s;
  }
  int b = bh / NHEADS, h = bh - b * NHEADS;
#pragma unroll
  for (int i = 0; i < 2; i++) {
#pragma unroll
    for (int r = 0; r < 4; r++) {
      float inv = 1.f / __shfl(rsum[i], quad * 4 + r);
      int q = q0 + i * 16 + quad * 4 + r;
      size_t base = (size_t)(b * SEQ + q) * DIM + h * HDIM;
#pragma unroll
      for (int di = 0; di < 4; di++)
        Ctx[base + di * 16 + l15] = f2bf(o[i][di][r] * inv);
    }
  }
}

// ---------------- residual + LayerNorm: 4 tokens/block, one wave per token ----------------

__launch_bounds__(256)
__global__ void ln_kernel(const float* __restrict__ x, const float* __restrict__ y,
                          const float* __restrict__ gamma, const float* __restrict__ beta,
                          float* __restrict__ out) {
  const int tok = blockIdx.x * 4 + (threadIdx.x >> 6);
  const int lane = threadIdx.x & 63;
  const float4* X = (const float4*)(x + (size_t)tok * DIM);
  const float4* Y = (const float4*)(y + (size_t)tok * DIM);
  const float4* G = (const float4*)gamma;
  const float4* Bt = (const float4*)beta;
  float4* O = (float4*)(out + (size_t)tok * DIM);

  float4 h[3];
  float s = 0.f;
#pragma unroll
  for (int i = 0; i < 3; i++) {
    float4 a = X[i * 64 + lane], b = Y[i * 64 + lane];
    h[i].x = a.x + b.x; h[i].y = a.y + b.y; h[i].z = a.z + b.z; h[i].w = a.w + b.w;
    s += h[i].x + h[i].y + h[i].z + h[i].w;
  }
#pragma unroll
  for (int off = 32; off >= 1; off >>= 1) s += __shfl_xor(s, off);
  float mu = s * (1.f / DIM);
  float v = 0.f;
#pragma unroll
  for (int i = 0; i < 3; i++) {
    h[i].x -= mu; h[i].y -= mu; h[i].z -= mu; h[i].w -= mu;
    v += h[i].x * h[i].x + h[i].y * h[i].y + h[i].z * h[i].z + h[i].w * h[i].w;
  }
#pragma unroll
  for (int off = 32; off >= 1; off >>= 1) v += __shfl_xor(v, off);
  float rstd = rsqrtf(v * (1.f / DIM) + 1e-5f);
#pragma unroll
  for (int i = 0; i < 3; i++) {
    float4 g = G[i * 64 + lane], bt = Bt[i * 64 + lane];
    float4 r;
    r.x = h[i].x * rstd * g.x + bt.x;
    r.y = h[i].y * rstd * g.y + bt.y;
    r.z = h[i].z * rstd * g.z + bt.z;
    r.w = h[i].w * rstd * g.w + bt.w;
    O[i * 64 + lane] = r;
  }
}

// ---------------- launch ----------------

extern "C" void kernel_launch(void* const* d_in, const int* in_sizes, int n_in,
                              void* d_out, int out_size, void* d_ws, size_t ws_size,
                              hipStream_t stream) {
  const float* x  = (const float*)d_in[0];
  const float* Wq = (const float*)d_in[1];
  const float* bq = (const float*)d_in[2];
  const float* Wk = (const float*)d_in[3];
  const float* bk = (const float*)d_in[4];
  const float* Wv = (const float*)d_in[5];
  const float* bv = (const float*)d_in[6];
  const float* W1 = (const float*)d_in[7];
  const float* b1 = (const float*)d_in[8];
  const float* W2 = (const float*)d_in[9];
  const float* b2 = (const float*)d_in[10];
  const float* gamma = (const float*)d_in[11];
  const float* beta  = (const float*)d_in[12];

  char* ws = (char*)d_ws;
  u16* xb   = (u16*)ws;           ws += (size_t)NTOK * DIM * 2;
  u16* Wqkvt = (u16*)ws;          ws += (size_t)DIM * DIM * 3 * 2;
  u16* W1t  = (u16*)ws;           ws += (size_t)DIM * FF * 2;
  u16* W2t  = (u16*)ws;           ws += (size_t)DIM * FF * 2;
  float* bqkv = (float*)ws;       ws += (size_t)3 * DIM * 4;
  u16* Qb   = (u16*)ws;           ws += (size_t)NTOK * DIM * 2;   // Q,K,V contiguous
  u16* Kbf  = (u16*)ws;           ws += (size_t)NTOK * DIM * 2;
  u16* Vtb  = (u16*)ws;           ws += (size_t)NTOK * DIM * 2;
  u16* Ctx  = (u16*)ws;           ws += (size_t)NTOK * DIM * 2;
  u16* H1   = (u16*)ws;           ws += (size_t)NTOK * FF * 2;
  float* Y2 = (float*)ws;         ws += (size_t)NTOK * DIM * 4;

  // prep
  conv_bf16<<<(NTOK * DIM) / 1024, 256, 0, stream>>>(x, xb, NTOK * DIM);
  prep_weights<<<4041, 256, 0, stream>>>(Wq, Wk, Wv, W1, W2, bq, bk, bv,
                                         Wqkvt, W1t, W2t, bqkv);

  // fused QKV projection (N = 2304): 18 N-tiles x 64 M-tiles, XCD-swizzled flat grid
  gemm128<5, 18><<<1152, 256, 0, stream>>>(xb, Wqkvt, bqkv, Qb, DIM);

  // attention (768 flat blocks, XCD-swizzled inside)
  attn<<<768, 256, 0, stream>>>(Qb, Kbf, Vtb, Ctx);

  // MLP
  gemm128<3, 12><<<768, 256, 0, stream>>>(Ctx, W1t, b1, H1, DIM);
  gemm128<4, 6><<<384, 256, 0, stream>>>(H1, W2t, b2, Y2, FF);

  // residual + LN
  ln_kernel<<<NTOK / 4, 256, 0, stream>>>(x, Y2, gamma, beta, (float*)d_out);
}